// Round 12
// baseline (233.939 us; speedup 1.0000x reference)
//
#include <hip/hip_runtime.h>
#include <hip/hip_bf16.h>

// Problem constants (from reference): B=2, S=2048, D=1024, H=16, DK=64
#define B_  2
#define S_  2048
#define D_  1024
#define H_  16
#define DK_ 64

using bf16 = __hip_bfloat16;
typedef __bf16 bf16x8 __attribute__((ext_vector_type(8)));
typedef float  f32x4  __attribute__((ext_vector_type(4)));
typedef float  f32x16 __attribute__((ext_vector_type(16)));

__device__ inline void st1(float* p, float v) { *p = v; }
__device__ inline void st1(bf16*  p, float v) { *p = __float2bfloat16(v); }

// Async global->LDS, 16B per lane. LDS dest = wave-uniform base + lane*16.
__device__ inline void gll16(const void* g, void* l) {
    __builtin_amdgcn_global_load_lds(
        (const __attribute__((address_space(1))) unsigned int*)g,
        (__attribute__((address_space(3))) unsigned int*)l, 16, 0, 0);
}

__device__ inline f32x16 mfma32(bf16x8 a, bf16x8 b, f32x16 c) {
    return __builtin_amdgcn_mfma_f32_32x32x16_bf16(a, b, c, 0, 0, 0);
}

// v_cvt_pk_bf16_f32: low 16 = bf16(lo), high 16 = bf16(hi). No builtin (m240).
__device__ inline unsigned cvtpk(float lo, float hi) {
    unsigned r;
    asm("v_cvt_pk_bf16_f32 %0, %1, %2" : "=v"(r) : "v"(lo), "v"(hi));
    return r;
}

// v_permlane32_swap_b32 D, S: D.lanes[32:63] <-> S.lanes[0:31].
__device__ inline void plswap(unsigned &d, unsigned &s) {
    asm volatile("v_permlane32_swap_b32 %0, %1" : "+v"(d), "+v"(s));
}

// ---------------------------------------------------------------------------
// f32 -> bf16 conversion: weights only now (Wq,Wk,Wv,Wo). The q/k/v
// conversion is FUSED into the QKV GEMM (R12): it was 72 MB of traffic that
// existed only to pre-convert the GEMM's A operand.
// ---------------------------------------------------------------------------
__global__ __launch_bounds__(256) void cvt_kernel(
    const float* __restrict__ s0, const float* __restrict__ s1,
    const float* __restrict__ s2, const float* __restrict__ s3,
    bf16* __restrict__ d0, bf16* __restrict__ d1,
    bf16* __restrict__ d2, bf16* __restrict__ d3, int n)
{
    const int z = blockIdx.y;
    const float* s; bf16* d;
    switch (z) {
        case 0: s = s0; d = d0; break;
        case 1: s = s1; d = d1; break;
        case 2: s = s2; d = d2; break;
        default: s = s3; d = d3; break;
    }
    const int idx = (blockIdx.x * 256 + threadIdx.x) * 4;
    if (idx < n) {
        const float4 v = *reinterpret_cast<const float4*>(s + idx);
        union { ushort4 u; __bf16 h[4]; } r;
        r.h[0] = (__bf16)v.x; r.h[1] = (__bf16)v.y;
        r.h[2] = (__bf16)v.z; r.h[3] = (__bf16)v.w;
        *reinterpret_cast<ushort4*>(d + idx) = r.u;
    }
}

// ---------------------------------------------------------------------------
// GEMM: C[M,N] = A[M,K] @ W[N,K]^T + bias[N]; W bf16; bias f32; C per TC.
// A is TA = float (QKV: reads original f32 inputs, converts in-register at
// fragment load via v_cvt_pk_bf16_f32) or bf16 (out-proj: unchanged path).
// m97 structure, BK=64 (two 32-col halves per interval), 4 waves 2x2.
// f32-A staging uses the attn-validated XOR swizzle (src col-group =
// (lane&7)^(lane>>3); read at group G^(row&7)) -> A-reads stay at the
// uniform 8-words/bank floor (unswizzled f32 rows = 128 B would put all 16
// rows of a fragment on the same 4 banks: 2x the floor).
// R7 win kept: 1-D grid + T1 XCD-locality swizzle.
// ---------------------------------------------------------------------------
template <typename TA, typename TC, bool VT3, int BM>
__global__ __launch_bounds__(256, BM == 128 ? 3 : 4) void gemm_bt_kernel(
    const TA* __restrict__ A0, const TA* __restrict__ A1, const TA* __restrict__ A2,
    const bf16* __restrict__ W0, const bf16* __restrict__ W1, const bf16* __restrict__ W2,
    const float* __restrict__ b0, const float* __restrict__ b1, const float* __restrict__ b2,
    TC* __restrict__ C0, TC* __restrict__ C1, TC* __restrict__ C2,
    int M, int N, int K)
{
    constexpr bool AF32 = (sizeof(TA) == 4);

    // XCD-locality decode (nx must be 8; gridDim.x = 8*ny*nz, %64 == 0)
    const int bid  = blockIdx.x;
    const int ny   = M / BM;
    const int tile = (bid & 7) * (gridDim.x >> 3) + (bid >> 3);
    const int x    = tile & 7;          // n-block: fastest within an XCD
    const int pair = tile >> 3;         // (y,z)
    const int y    = pair % ny;
    const int z    = pair / ny;

    const TA*    A    = (z == 0) ? A0 : (z == 1) ? A1 : A2;
    const bf16*  W    = (z == 0) ? W0 : (z == 1) ? W1 : W2;
    const float* bias = (z == 0) ? b0 : (z == 1) ? b1 : b2;
    TC*          C    = (z == 0) ? C0 : (z == 1) ? C1 : C2;

    __shared__ TA   As[2][BM][32];   // f32: 32 KB / bf16: 16|8 KB
    __shared__ bf16 Bs[2][128][32];

    const int t    = threadIdx.x;
    const int lane = t & 63;
    const int wave = t >> 6;
    const int quad = lane >> 4;
    const int l16  = lane & 15;
    const int wm   = wave >> 1;
    const int wn   = wave & 1;

    const int m0 = y * BM;
    const int n0 = x * 128;

    constexpr int RPW = BM / 4;          // A rows staged per wave
    constexpr int MI  = BM / 32;         // 16-row fragments per wave in M
    int ar0, ac0;
    if constexpr (AF32) { ar0 = wave * RPW + (lane >> 3); ac0 = ((lane & 7) ^ (lane >> 3)) * 4; }
    else                { ar0 = wave * RPW + (lane >> 2); ac0 = (lane & 3) * 8; }
    const int br0 = wave * 32 + (lane >> 2);
    const int bc0 = (lane & 3) * 8;
    const TA*   Ab = A + (size_t)(m0 + ar0) * K + ac0;
    const bf16* Bb = W + (size_t)(n0 + br0) * K + bc0;

    f32x4 acc[MI][4] = {};

    for (int kt = 0; kt < K; kt += 64) {
        __syncthreads();
#pragma unroll
        for (int hh = 0; hh < 2; hh++) {
            const int ko = kt + 32 * hh;
            if constexpr (AF32) {
#pragma unroll
                for (int r = 0; r < RPW; r += 8)
                    gll16(Ab + (size_t)r * K + ko, &As[hh][wave * RPW + r][0]);
            } else {
                gll16(Ab + ko, &As[hh][wave * RPW][0]);
                if constexpr (BM == 128) gll16(Ab + 16 * K + ko, &As[hh][wave * RPW + 16][0]);
            }
            gll16(Bb + ko, &Bs[hh][wave * 32][0]);
            gll16(Bb + 16 * K + ko, &Bs[hh][wave * 32 + 16][0]);
        }
        __syncthreads();

#pragma unroll
        for (int hh = 0; hh < 2; hh++) {
            bf16x8 af[MI], bfr[4];
#pragma unroll
            for (int mi = 0; mi < MI; mi++) {
                const int row = wm * (BM / 2) + mi * 16 + l16;
                if constexpr (AF32) {
                    const int sw = l16 & 7;   // == row&7 (row = mult16 + l16)
                    const float4 a = *reinterpret_cast<const float4*>(
                        &As[hh][row][((2 * quad) ^ sw) * 4]);
                    const float4 b = *reinterpret_cast<const float4*>(
                        &As[hh][row][((2 * quad + 1) ^ sw) * 4]);
                    union { unsigned u[4]; bf16x8 v; } r;
                    r.u[0] = cvtpk(a.x, a.y); r.u[1] = cvtpk(a.z, a.w);
                    r.u[2] = cvtpk(b.x, b.y); r.u[3] = cvtpk(b.z, b.w);
                    af[mi] = r.v;
                } else {
                    af[mi] = *reinterpret_cast<const bf16x8*>(&As[hh][row][quad * 8]);
                }
            }
#pragma unroll
            for (int ni = 0; ni < 4; ni++)
                bfr[ni] = *reinterpret_cast<const bf16x8*>(&Bs[hh][wn * 64 + ni * 16 + l16][quad * 8]);
#pragma unroll
            for (int mi = 0; mi < MI; mi++)
#pragma unroll
                for (int ni = 0; ni < 4; ni++)
                    acc[mi][ni] = __builtin_amdgcn_mfma_f32_16x16x32_bf16(
                        af[mi], bfr[ni], acc[mi][ni], 0, 0, 0);
        }
    }

    if (VT3 && z == 2) {
#pragma unroll
        for (int ni = 0; ni < 4; ni++) {
            const int col = n0 + wn * 64 + ni * 16 + l16;
            const float bvv = bias[col];
            const int hh = col >> 6, dh = col & 63;
#pragma unroll
            for (int mi = 0; mi < MI; mi++) {
                const int rb  = m0 + wm * (BM / 2) + mi * 16 + quad * 4;
                const int bb  = rb >> 11;
                const int tok = rb & (S_ - 1);
                union { ushort4 u; __bf16 h[4]; } pk;
#pragma unroll
                for (int i = 0; i < 4; i++)
                    pk.h[i] = (__bf16)(acc[mi][ni][i] + bvv);
                bf16* vt = (bf16*)C + ((size_t)(bb * H_ + hh) * DK_ + dh) * S_ + tok;
                *reinterpret_cast<ushort4*>(vt) = pk.u;
            }
        }
    } else {
#pragma unroll
        for (int ni = 0; ni < 4; ni++) {
            const int col = n0 + wn * 64 + ni * 16 + l16;
            const float bvv = bias[col];
#pragma unroll
            for (int mi = 0; mi < MI; mi++) {
#pragma unroll
                for (int i = 0; i < 4; i++) {
                    const int row = m0 + wm * (BM / 2) + mi * 16 + quad * 4 + i;
                    st1(&C[(size_t)row * N + col], acc[mi][ni][i] + bvv);
                }
            }
        }
    }
}

// ---------------------------------------------------------------------------
// Flash attention (causal), R9 VERBATIM (best-measured). 512 single-tile
// blocks (2/CU), 128-row tiles, 4 waves, long-first order; KVBLK=128 as two
// 64-key halves per interval (16 intervals max); stage(it+1) at top, compute
// both halves, vmcnt(0)+barrier at bottom (drain covered by the 2x compute).
// Math: 32x32 swapped QK^T, T12 in-register pack. LDS staging's role here
// is REQUEST COALESCING (R10: direct per-lane loads were TA-bound, 2.5x
// worse). AO aliases Qp: one block owns each tile; Q read only in the
// owning block's prologue; disjoint tile writes. Race-free.
// ---------------------------------------------------------------------------
__global__ __launch_bounds__(256, 2) void attn_kernel(
    const bf16* __restrict__ Qp, const bf16* __restrict__ Kp,
    const bf16* __restrict__ VT, bf16* __restrict__ AO)
{
    const int t    = threadIdx.x;
    const int lane = t & 63;
    const int wave = t >> 6;          // 0..3
    const int r31  = lane & 31;
    const int hl   = lane >> 5;       // half-lane
    const int l7   = lane & 7;

    // global long-first 1-D ordering over 512 single-tile blocks
    const int bid = blockIdx.x;
    int til, hb;
    if (bid < 256) { til = 15 - (bid >> 5); hb = bid & 31; }
    else           { til = (bid - 256) >> 5; hb = (bid - 256) & 31; }
    const int h = hb & 15;
    const int b = hb >> 4;
    const size_t bh = (size_t)b * S_ * D_ + (size_t)h * DK_;
    const bf16* vtb = VT + (size_t)(b * H_ + h) * DK_ * S_;

    __shared__ bf16 Ks[2][2][64][64];  // [buf][half][key][dk]  16 KB per buf
    __shared__ bf16 Vs[2][2][64][64];  // [buf][half][dh][key]  16 KB per buf

    // staging lane constants: lane -> (row-within-8, swizzled col-group)
    const int sR  = lane >> 3;                // 0..7
    const int scg = ((lane & 7) ^ sR) * 8;    // element offset, XOR swizzle

    const float QSC = 0.18033688f;   // 0.125 * log2(e)
    const float NEG = -1e30f;

    bf16x8 ONES;
#pragma unroll
    for (int j = 0; j < 8; j++) ONES[j] = (__bf16)1.0f;

    const int ntot = til + 1;         // causal: 128-key chunks 0..til

    // Q fragments: qf[d] = Q[q=r31][dk=16d+8hl+j] * QSC  (wave's 32 rows)
    bf16x8 qf[4];
    {
        const bf16* qr = Qp + bh + (size_t)(til * 128 + wave * 32 + r31) * D_ + 8 * hl;
#pragma unroll
        for (int d = 0; d < 4; d++) {
            qf[d] = *reinterpret_cast<const bf16x8*>(qr + 16 * d);
#pragma unroll
            for (int j = 0; j < 8; j++) qf[d][j] = (__bf16)((float)qf[d][j] * QSC);
        }
    }

    f32x16 oacc0 = {}, oacc1 = {}, lacc = {};

    // stage 128-key chunk `slot` into buf slot&1 (two 64-key halves);
    // per wave: 2 halves x (2 gll16 K + 2 gll16 V) = 8 gll16
    auto stage = [&](int slot) {
        const int k0n = slot * 128;
        const int bb  = slot & 1;
#pragma unroll
        for (int half = 0; half < 2; half++) {
            const int kh = k0n + 64 * half;
#pragma unroll
            for (int j = 0; j < 2; j++) {
                const int rb = wave * 16 + j * 8;
                gll16(Kp + bh + (size_t)(kh + rb + sR) * D_ + scg, &Ks[bb][half][rb][0]);
                gll16(vtb + (size_t)(rb + sR) * S_ + kh + scg,     &Vs[bb][half][rb][0]);
            }
        }
    };

    // prologue: chunk 0 staged and published
    stage(0);
    asm volatile("s_waitcnt vmcnt(0)" ::: "memory");
    __builtin_amdgcn_s_barrier();

    for (int it = 0; it < ntot; it++) {
        if (it + 1 < ntot) stage(it + 1);   // flight = this (2x) compute

        const int buf = it & 1;
        const int qw0 = til * 128 + wave * 32;

#pragma unroll
        for (int hh = 0; hh < 2; hh++) {
            const int k0 = it * 128 + 64 * hh;
            if (k0 > qw0 + 31) continue;    // fully masked for this wave

            // QK^T swapped: s0/s1 = S^T for keys 0-31 / 32-63 of the half
            f32x16 s0 = {}, s1 = {};
#pragma unroll
            for (int d = 0; d < 4; d++) {
                const int g = ((2 * d + hl) ^ l7) * 8;
                const bf16x8 kf0 = *reinterpret_cast<const bf16x8*>(&Ks[buf][hh][r31][g]);
                const bf16x8 kf1 = *reinterpret_cast<const bf16x8*>(&Ks[buf][hh][32 + r31][g]);
                s0 = mfma32(kf0, qf[d], s0);
                s1 = mfma32(kf1, qf[d], s1);
            }

            // causal mask (diagonal halves only); key = k0+32G+(r&3)+8*(r>>2)+4hl
            if (k0 + 63 > qw0) {
                const int qg = qw0 + r31;
                const int kb = k0 + 4 * hl;
#pragma unroll
                for (int r = 0; r < 16; r++) {
                    const int ko = (r & 3) + 8 * (r >> 2);
                    s0[r] = (kb + ko      <= qg) ? s0[r] : NEG;
                    s1[r] = (kb + 32 + ko <= qg) ? s1[r] : NEG;
                }
            }

            // exp2 (no max-sub, validated)
#pragma unroll
            for (int r = 0; r < 16; r++) {
                s0[r] = __builtin_amdgcn_exp2f(s0[r]);
                s1[r] = __builtin_amdgcn_exp2f(s1[r]);
            }

            // pack P -> PV A-fragments (T12: cvt_pk + permlane32_swap)
            bf16x8 pa[4];
#pragma unroll
            for (int G = 0; G < 2; G++) {
#pragma unroll
                for (int tt = 0; tt < 2; tt++) {
                    unsigned a01, a23, a45, a67;
                    if (G == 0) {
                        a01 = cvtpk(s0[8*tt+0], s0[8*tt+1]);
                        a23 = cvtpk(s0[8*tt+2], s0[8*tt+3]);
                        a45 = cvtpk(s0[8*tt+4], s0[8*tt+5]);
                        a67 = cvtpk(s0[8*tt+6], s0[8*tt+7]);
                    } else {
                        a01 = cvtpk(s1[8*tt+0], s1[8*tt+1]);
                        a23 = cvtpk(s1[8*tt+2], s1[8*tt+3]);
                        a45 = cvtpk(s1[8*tt+4], s1[8*tt+5]);
                        a67 = cvtpk(s1[8*tt+6], s1[8*tt+7]);
                    }
                    plswap(a01, a45);   // a01 -> w0, a45 -> w2
                    plswap(a23, a67);   // a23 -> w1, a67 -> w3
                    union { unsigned u[4]; bf16x8 v; } pu;
                    pu.u[0] = a01; pu.u[1] = a23; pu.u[2] = a45; pu.u[3] = a67;
                    pa[2 * G + tt] = pu.v;
                }
            }

            // PV + row-sum from staged V^T (swizzled b128 reads)
#pragma unroll
            for (int s = 0; s < 4; s++) {
                const int g = ((2 * s + hl) ^ l7) * 8;
                const bf16x8 vf0 = *reinterpret_cast<const bf16x8*>(&Vs[buf][hh][r31][g]);
                const bf16x8 vf1 = *reinterpret_cast<const bf16x8*>(&Vs[buf][hh][32 + r31][g]);
                oacc0 = mfma32(pa[s], vf0, oacc0);
                oacc1 = mfma32(pa[s], vf1, oacc1);
                lacc  = mfma32(pa[s], ONES, lacc);
            }
        }

        // publish: own DMA landed + all waves done reading buf it&1
        asm volatile("s_waitcnt vmcnt(0)" ::: "memory");
        __builtin_amdgcn_s_barrier();
    }

    // epilogue
    {
        const int qb0 = til * 128 + wave * 32;
#pragma unroll
        for (int r = 0; r < 16; r++) {
            const int q = qb0 + (r & 3) + 8 * (r >> 2) + 4 * hl;
            const float inv = 1.0f / lacc[r];
            AO[bh + (size_t)q * D_ + r31]      = __float2bfloat16(oacc0[r] * inv);
            AO[bh + (size_t)q * D_ + 32 + r31] = __float2bfloat16(oacc1[r] * inv);
        }
    }
}

// ---------------------------------------------------------------------------
extern "C" void kernel_launch(void* const* d_in, const int* in_sizes, int n_in,
                              void* d_out, int out_size, void* d_ws, size_t ws_size,
                              hipStream_t stream)
{
    const float* q  = (const float*)d_in[0];
    const float* k  = (const float*)d_in[1];
    const float* v  = (const float*)d_in[2];
    // d_in[3]: causal mask (int32 tril) — applied analytically
    const float* Wq = (const float*)d_in[4];
    const float* bq = (const float*)d_in[5];
    const float* Wk = (const float*)d_in[6];
    const float* bk = (const float*)d_in[7];
    const float* Wv = (const float*)d_in[8];
    const float* bv = (const float*)d_in[9];
    const float* Wo = (const float*)d_in[10];
    const float* bo = (const float*)d_in[11];
    float* out = (float*)d_out;

    bf16* ws = (bf16*)d_ws;
    const size_t MD = (size_t)(B_ * S_) * D_;   // 4,194,304
    const size_t WN = (size_t)D_ * D_;          // 1,048,576
    bf16* wqb = ws;
    bf16* wkb = wqb + WN;
    bf16* wvb = wkb + WN;
    bf16* wob = wvb + WN;
    bf16* Qp  = wob + WN;
    bf16* Kp  = Qp + MD;
    bf16* VT  = Kp + MD;    // total 3*MD + 4*WN ~= 33.6 MB
    bf16* AO  = Qp;         // alias: safe (see attn_kernel note)

    const int M = B_ * S_;  // 4096

    // 1) convert weights to bf16 (q/k/v conversion fused into the QKV GEMM)
    cvt_kernel<<<dim3((int)(WN / 4 / 256), 4), 256, 0, stream>>>(
        Wq, Wk, Wv, Wo, wqb, wkb, wvb, wob, (int)WN);

    // 2) QKV projections straight from f32 inputs (in-register A conversion),
    //    XCD-swizzled 1-D grid (768 = 8x * 32y * 3z), BK=64
    gemm_bt_kernel<float, bf16, true, 128><<<dim3(768), 256, 0, stream>>>(
        q, k, v, wqb, wkb, wvb, bq, bk, bv, Qp, Kp, VT, M, D_, D_);

    // 3) causal flash attention: R9 verbatim (512 blocks, KVBLK=128 staged)
    attn_kernel<<<dim3(512), 256, 0, stream>>>(Qp, Kp, VT, AO);

    // 4) output projection -> f32 out, XCD-swizzled 1-D grid (512), BK=64
    gemm_bt_kernel<bf16, float, false, 64><<<dim3(512), 256, 0, stream>>>(
        AO, AO, AO, wob, wob, wob, bo, bo, bo, out, out, out, M, D_, D_);
}

// Round 13
// 212.774 us; speedup vs baseline: 1.0995x; 1.0995x over previous
//
#include <hip/hip_runtime.h>
#include <hip/hip_bf16.h>

// Problem constants (from reference): B=2, S=2048, D=1024, H=16, DK=64
#define B_  2
#define S_  2048
#define D_  1024
#define H_  16
#define DK_ 64

using bf16 = __hip_bfloat16;
typedef __bf16 bf16x8 __attribute__((ext_vector_type(8)));
typedef float  f32x4  __attribute__((ext_vector_type(4)));
typedef float  f32x16 __attribute__((ext_vector_type(16)));

__device__ inline void st1(float* p, float v) { *p = v; }
__device__ inline void st1(bf16*  p, float v) { *p = __float2bfloat16(v); }

// Async global->LDS, 16B per lane. LDS dest = wave-uniform base + lane*16.
__device__ inline void gll16(const bf16* g, bf16* l) {
    __builtin_amdgcn_global_load_lds(
        (const __attribute__((address_space(1))) unsigned int*)g,
        (__attribute__((address_space(3))) unsigned int*)l, 16, 0, 0);
}

__device__ inline f32x16 mfma32(bf16x8 a, bf16x8 b, f32x16 c) {
    return __builtin_amdgcn_mfma_f32_32x32x16_bf16(a, b, c, 0, 0, 0);
}

// v_cvt_pk_bf16_f32: low 16 = bf16(lo), high 16 = bf16(hi). No builtin (m240).
__device__ inline unsigned cvtpk(float lo, float hi) {
    unsigned r;
    asm("v_cvt_pk_bf16_f32 %0, %1, %2" : "=v"(r) : "v"(lo), "v"(hi));
    return r;
}

// v_permlane32_swap_b32 D, S: D.lanes[32:63] <-> S.lanes[0:31].
__device__ inline void plswap(unsigned &d, unsigned &s) {
    asm volatile("v_permlane32_swap_b32 %0, %1" : "+v"(d), "+v"(s));
}

// ---------------------------------------------------------------------------
// f32 -> bf16 conversion: 7 regions (q,k,v = nbig; Wq,Wk,Wv,Wo = nsmall).
// R12 post-mortem: fusing the q/k/v conversion into the GEMM regressed 2x
// (wrong f32 swizzle -> 4.7M bank conflicts; 3x A-staging ops; cvt_pk on the
// K-loop critical path). Conversion belongs in this bandwidth-cheap
// streaming pass. REVERTED to the R11 structure.
// ---------------------------------------------------------------------------
__global__ __launch_bounds__(256) void cvt_kernel(
    const float* __restrict__ s0, const float* __restrict__ s1,
    const float* __restrict__ s2, const float* __restrict__ s3,
    const float* __restrict__ s4, const float* __restrict__ s5,
    const float* __restrict__ s6,
    bf16* __restrict__ d0, bf16* __restrict__ d1, bf16* __restrict__ d2,
    bf16* __restrict__ d3, bf16* __restrict__ d4, bf16* __restrict__ d5,
    bf16* __restrict__ d6, int nbig, int nsmall)
{
    const int z = blockIdx.y;
    const float* s; bf16* d; int n;
    switch (z) {
        case 0: s = s0; d = d0; n = nbig;   break;
        case 1: s = s1; d = d1; n = nbig;   break;
        case 2: s = s2; d = d2; n = nbig;   break;
        case 3: s = s3; d = d3; n = nsmall; break;
        case 4: s = s4; d = d4; n = nsmall; break;
        case 5: s = s5; d = d5; n = nsmall; break;
        default: s = s6; d = d6; n = nsmall; break;
    }
    const int idx = (blockIdx.x * 256 + threadIdx.x) * 4;
    if (idx < n) {
        const float4 v = *reinterpret_cast<const float4*>(s + idx);
        union { ushort4 u; __bf16 h[4]; } r;
        r.h[0] = (__bf16)v.x; r.h[1] = (__bf16)v.y;
        r.h[2] = (__bf16)v.z; r.h[3] = (__bf16)v.w;
        *reinterpret_cast<ushort4*>(d + idx) = r.u;
    }
}

// ---------------------------------------------------------------------------
// GEMM: C[M,N] = A[M,K] @ W[N,K]^T + bias[N]; A,W bf16; bias f32; C per TC.
// m97 structure, BK=64 (two 32-col halves per interval), 4 waves 2x2.
// R7 win kept: 1-D grid + T1 XCD-locality swizzle (8 n-blocks sharing an
// A row-panel run consecutively on the same XCD). R11-measured config.
// ---------------------------------------------------------------------------
template <typename TC, bool VT3, int BM>
__global__ __launch_bounds__(256, BM == 128 ? 3 : 4) void gemm_bt_kernel(
    const bf16* __restrict__ A0, const bf16* __restrict__ A1, const bf16* __restrict__ A2,
    const bf16* __restrict__ W0, const bf16* __restrict__ W1, const bf16* __restrict__ W2,
    const float* __restrict__ b0, const float* __restrict__ b1, const float* __restrict__ b2,
    TC* __restrict__ C0, TC* __restrict__ C1, TC* __restrict__ C2,
    int M, int N, int K)
{
    // XCD-locality decode (nx must be 8; gridDim.x = 8*ny*nz, %64 == 0)
    const int bid  = blockIdx.x;
    const int ny   = M / BM;
    const int tile = (bid & 7) * (gridDim.x >> 3) + (bid >> 3);
    const int x    = tile & 7;          // n-block: fastest within an XCD
    const int pair = tile >> 3;         // (y,z)
    const int y    = pair % ny;
    const int z    = pair / ny;

    const bf16*  A    = (z == 0) ? A0 : (z == 1) ? A1 : A2;
    const bf16*  W    = (z == 0) ? W0 : (z == 1) ? W1 : W2;
    const float* bias = (z == 0) ? b0 : (z == 1) ? b1 : b2;
    TC*          C    = (z == 0) ? C0 : (z == 1) ? C1 : C2;

    __shared__ bf16 As[2][BM][32];   // [half][row][32]  64 B rows, NO pad
    __shared__ bf16 Bs[2][128][32];

    const int t    = threadIdx.x;
    const int lane = t & 63;
    const int wave = t >> 6;
    const int quad = lane >> 4;
    const int l16  = lane & 15;
    const int wm   = wave >> 1;
    const int wn   = wave & 1;

    const int m0 = y * BM;
    const int n0 = x * 128;

    constexpr int RPW = BM / 4;          // A rows staged per wave
    constexpr int MI  = BM / 32;         // 16-row fragments per wave in M
    const int ar0 = wave * RPW + (lane >> 2);
    const int br0 = wave * 32  + (lane >> 2);
    const int c0  = (lane & 3) * 8;
    const bf16* Ab = A + (size_t)(m0 + ar0) * K + c0;
    const bf16* Bb = W + (size_t)(n0 + br0) * K + c0;

    f32x4 acc[MI][4] = {};

    for (int kt = 0; kt < K; kt += 64) {
        __syncthreads();
#pragma unroll
        for (int hh = 0; hh < 2; hh++) {
            const int ko = kt + 32 * hh;
            gll16(Ab + ko, &As[hh][wave * RPW][0]);
            if constexpr (BM == 128) gll16(Ab + 16 * K + ko, &As[hh][wave * RPW + 16][0]);
            gll16(Bb + ko, &Bs[hh][wave * 32][0]);
            gll16(Bb + 16 * K + ko, &Bs[hh][wave * 32 + 16][0]);
        }
        __syncthreads();

#pragma unroll
        for (int hh = 0; hh < 2; hh++) {
            bf16x8 af[MI], bfr[4];
#pragma unroll
            for (int mi = 0; mi < MI; mi++)
                af[mi] = *reinterpret_cast<const bf16x8*>(&As[hh][wm * (BM / 2) + mi * 16 + l16][quad * 8]);
#pragma unroll
            for (int ni = 0; ni < 4; ni++)
                bfr[ni] = *reinterpret_cast<const bf16x8*>(&Bs[hh][wn * 64 + ni * 16 + l16][quad * 8]);
#pragma unroll
            for (int mi = 0; mi < MI; mi++)
#pragma unroll
                for (int ni = 0; ni < 4; ni++)
                    acc[mi][ni] = __builtin_amdgcn_mfma_f32_16x16x32_bf16(
                        af[mi], bfr[ni], acc[mi][ni], 0, 0, 0);
        }
    }

    if (VT3 && z == 2) {
#pragma unroll
        for (int ni = 0; ni < 4; ni++) {
            const int col = n0 + wn * 64 + ni * 16 + l16;
            const float bvv = bias[col];
            const int hh = col >> 6, dh = col & 63;
#pragma unroll
            for (int mi = 0; mi < MI; mi++) {
                const int rb  = m0 + wm * (BM / 2) + mi * 16 + quad * 4;
                const int bb  = rb >> 11;
                const int tok = rb & (S_ - 1);
                union { ushort4 u; __bf16 h[4]; } pk;
#pragma unroll
                for (int i = 0; i < 4; i++)
                    pk.h[i] = (__bf16)(acc[mi][ni][i] + bvv);
                bf16* vt = (bf16*)C + ((size_t)(bb * H_ + hh) * DK_ + dh) * S_ + tok;
                *reinterpret_cast<ushort4*>(vt) = pk.u;
            }
        }
    } else {
#pragma unroll
        for (int ni = 0; ni < 4; ni++) {
            const int col = n0 + wn * 64 + ni * 16 + l16;
            const float bvv = bias[col];
#pragma unroll
            for (int mi = 0; mi < MI; mi++) {
#pragma unroll
                for (int i = 0; i < 4; i++) {
                    const int row = m0 + wm * (BM / 2) + mi * 16 + quad * 4 + i;
                    st1(&C[(size_t)row * N + col], acc[mi][ni][i] + bvv);
                }
            }
        }
    }
}

// ---------------------------------------------------------------------------
// Flash attention (causal), R13 = R9 + T5 s_setprio around MFMA clusters.
// T5 prerequisites hold here (catalog m191): 2 independent blocks/CU whose
// barrier groups drift (different ntot) + staging/compute role diversity ->
// the scheduler has something to arbitrate. Pure hint, zero correctness
// risk. GEMMs left untouched (m190: setprio null on lockstep GEMM).
// Structure: 512 single-tile blocks (2/CU), 128-row tiles, 4 waves,
// long-first order; KVBLK=128 as two 64-key halves per interval (16
// intervals max); stage(it+1) at top, compute both halves, vmcnt(0)+barrier
// at bottom (drain covered by the 2x compute). Math: 32x32 swapped QK^T,
// T12 in-register pack. LDS staging = REQUEST COALESCING (R10 lesson).
// AO aliases Qp: one block owns each tile; Q read only in the owning
// block's prologue; disjoint tile writes. Race-free.
// ---------------------------------------------------------------------------
__global__ __launch_bounds__(256, 2) void attn_kernel(
    const bf16* __restrict__ Qp, const bf16* __restrict__ Kp,
    const bf16* __restrict__ VT, bf16* __restrict__ AO)
{
    const int t    = threadIdx.x;
    const int lane = t & 63;
    const int wave = t >> 6;          // 0..3
    const int r31  = lane & 31;
    const int hl   = lane >> 5;       // half-lane
    const int l7   = lane & 7;

    // global long-first 1-D ordering over 512 single-tile blocks
    const int bid = blockIdx.x;
    int til, hb;
    if (bid < 256) { til = 15 - (bid >> 5); hb = bid & 31; }
    else           { til = (bid - 256) >> 5; hb = (bid - 256) & 31; }
    const int h = hb & 15;
    const int b = hb >> 4;
    const size_t bh = (size_t)b * S_ * D_ + (size_t)h * DK_;
    const bf16* vtb = VT + (size_t)(b * H_ + h) * DK_ * S_;

    __shared__ bf16 Ks[2][2][64][64];  // [buf][half][key][dk]  16 KB per buf
    __shared__ bf16 Vs[2][2][64][64];  // [buf][half][dh][key]  16 KB per buf

    // staging lane constants: lane -> (row-within-8, swizzled col-group)
    const int sR  = lane >> 3;                // 0..7
    const int scg = ((lane & 7) ^ sR) * 8;    // element offset, XOR swizzle

    const float QSC = 0.18033688f;   // 0.125 * log2(e)
    const float NEG = -1e30f;

    bf16x8 ONES;
#pragma unroll
    for (int j = 0; j < 8; j++) ONES[j] = (__bf16)1.0f;

    const int ntot = til + 1;         // causal: 128-key chunks 0..til

    // Q fragments: qf[d] = Q[q=r31][dk=16d+8hl+j] * QSC  (wave's 32 rows)
    bf16x8 qf[4];
    {
        const bf16* qr = Qp + bh + (size_t)(til * 128 + wave * 32 + r31) * D_ + 8 * hl;
#pragma unroll
        for (int d = 0; d < 4; d++) {
            qf[d] = *reinterpret_cast<const bf16x8*>(qr + 16 * d);
#pragma unroll
            for (int j = 0; j < 8; j++) qf[d][j] = (__bf16)((float)qf[d][j] * QSC);
        }
    }

    f32x16 oacc0 = {}, oacc1 = {}, lacc = {};

    // stage 128-key chunk `slot` into buf slot&1 (two 64-key halves);
    // per wave: 2 halves x (2 gll16 K + 2 gll16 V) = 8 gll16
    auto stage = [&](int slot) {
        const int k0n = slot * 128;
        const int bb  = slot & 1;
#pragma unroll
        for (int half = 0; half < 2; half++) {
            const int kh = k0n + 64 * half;
#pragma unroll
            for (int j = 0; j < 2; j++) {
                const int rb = wave * 16 + j * 8;
                gll16(Kp + bh + (size_t)(kh + rb + sR) * D_ + scg, &Ks[bb][half][rb][0]);
                gll16(vtb + (size_t)(rb + sR) * S_ + kh + scg,     &Vs[bb][half][rb][0]);
            }
        }
    };

    // prologue: chunk 0 staged and published
    stage(0);
    asm volatile("s_waitcnt vmcnt(0)" ::: "memory");
    __builtin_amdgcn_s_barrier();

    for (int it = 0; it < ntot; it++) {
        if (it + 1 < ntot) stage(it + 1);   // flight = this (2x) compute

        const int buf = it & 1;
        const int qw0 = til * 128 + wave * 32;

#pragma unroll
        for (int hh = 0; hh < 2; hh++) {
            const int k0 = it * 128 + 64 * hh;
            if (k0 > qw0 + 31) continue;    // fully masked for this wave

            // QK^T swapped: s0/s1 = S^T for keys 0-31 / 32-63 of the half
            f32x16 s0 = {}, s1 = {};
            __builtin_amdgcn_s_setprio(1);
#pragma unroll
            for (int d = 0; d < 4; d++) {
                const int g = ((2 * d + hl) ^ l7) * 8;
                const bf16x8 kf0 = *reinterpret_cast<const bf16x8*>(&Ks[buf][hh][r31][g]);
                const bf16x8 kf1 = *reinterpret_cast<const bf16x8*>(&Ks[buf][hh][32 + r31][g]);
                s0 = mfma32(kf0, qf[d], s0);
                s1 = mfma32(kf1, qf[d], s1);
            }
            __builtin_amdgcn_s_setprio(0);

            // causal mask (diagonal halves only); key = k0+32G+(r&3)+8*(r>>2)+4hl
            if (k0 + 63 > qw0) {
                const int qg = qw0 + r31;
                const int kb = k0 + 4 * hl;
#pragma unroll
                for (int r = 0; r < 16; r++) {
                    const int ko = (r & 3) + 8 * (r >> 2);
                    s0[r] = (kb + ko      <= qg) ? s0[r] : NEG;
                    s1[r] = (kb + 32 + ko <= qg) ? s1[r] : NEG;
                }
            }

            // exp2 (no max-sub, validated)
#pragma unroll
            for (int r = 0; r < 16; r++) {
                s0[r] = __builtin_amdgcn_exp2f(s0[r]);
                s1[r] = __builtin_amdgcn_exp2f(s1[r]);
            }

            // pack P -> PV A-fragments (T12: cvt_pk + permlane32_swap)
            bf16x8 pa[4];
#pragma unroll
            for (int G = 0; G < 2; G++) {
#pragma unroll
                for (int tt = 0; tt < 2; tt++) {
                    unsigned a01, a23, a45, a67;
                    if (G == 0) {
                        a01 = cvtpk(s0[8*tt+0], s0[8*tt+1]);
                        a23 = cvtpk(s0[8*tt+2], s0[8*tt+3]);
                        a45 = cvtpk(s0[8*tt+4], s0[8*tt+5]);
                        a67 = cvtpk(s0[8*tt+6], s0[8*tt+7]);
                    } else {
                        a01 = cvtpk(s1[8*tt+0], s1[8*tt+1]);
                        a23 = cvtpk(s1[8*tt+2], s1[8*tt+3]);
                        a45 = cvtpk(s1[8*tt+4], s1[8*tt+5]);
                        a67 = cvtpk(s1[8*tt+6], s1[8*tt+7]);
                    }
                    plswap(a01, a45);   // a01 -> w0, a45 -> w2
                    plswap(a23, a67);   // a23 -> w1, a67 -> w3
                    union { unsigned u[4]; bf16x8 v; } pu;
                    pu.u[0] = a01; pu.u[1] = a23; pu.u[2] = a45; pu.u[3] = a67;
                    pa[2 * G + tt] = pu.v;
                }
            }

            // PV + row-sum from staged V^T (swizzled b128 reads)
            __builtin_amdgcn_s_setprio(1);
#pragma unroll
            for (int s = 0; s < 4; s++) {
                const int g = ((2 * s + hl) ^ l7) * 8;
                const bf16x8 vf0 = *reinterpret_cast<const bf16x8*>(&Vs[buf][hh][r31][g]);
                const bf16x8 vf1 = *reinterpret_cast<const bf16x8*>(&Vs[buf][hh][32 + r31][g]);
                oacc0 = mfma32(pa[s], vf0, oacc0);
                oacc1 = mfma32(pa[s], vf1, oacc1);
                lacc  = mfma32(pa[s], ONES, lacc);
            }
            __builtin_amdgcn_s_setprio(0);
        }

        // publish: own DMA landed + all waves done reading buf it&1
        asm volatile("s_waitcnt vmcnt(0)" ::: "memory");
        __builtin_amdgcn_s_barrier();
    }

    // epilogue
    {
        const int qb0 = til * 128 + wave * 32;
#pragma unroll
        for (int r = 0; r < 16; r++) {
            const int q = qb0 + (r & 3) + 8 * (r >> 2) + 4 * hl;
            const float inv = 1.0f / lacc[r];
            AO[bh + (size_t)q * D_ + r31]      = __float2bfloat16(oacc0[r] * inv);
            AO[bh + (size_t)q * D_ + 32 + r31] = __float2bfloat16(oacc1[r] * inv);
        }
    }
}

// ---------------------------------------------------------------------------
extern "C" void kernel_launch(void* const* d_in, const int* in_sizes, int n_in,
                              void* d_out, int out_size, void* d_ws, size_t ws_size,
                              hipStream_t stream)
{
    const float* q  = (const float*)d_in[0];
    const float* k  = (const float*)d_in[1];
    const float* v  = (const float*)d_in[2];
    // d_in[3]: causal mask (int32 tril) — applied analytically
    const float* Wq = (const float*)d_in[4];
    const float* bq = (const float*)d_in[5];
    const float* Wk = (const float*)d_in[6];
    const float* bk = (const float*)d_in[7];
    const float* Wv = (const float*)d_in[8];
    const float* bv = (const float*)d_in[9];
    const float* Wo = (const float*)d_in[10];
    const float* bo = (const float*)d_in[11];
    float* out = (float*)d_out;

    bf16* ws = (bf16*)d_ws;
    const size_t MD = (size_t)(B_ * S_) * D_;   // 4,194,304
    const size_t WN = (size_t)D_ * D_;          // 1,048,576
    bf16* qb  = ws;
    bf16* kb  = ws + MD;
    bf16* vb  = ws + 2 * MD;
    bf16* wqb = ws + 3 * MD;
    bf16* wkb = wqb + WN;
    bf16* wvb = wkb + WN;
    bf16* wob = wvb + WN;
    bf16* Qp  = wob + WN;
    bf16* Kp  = Qp + MD;
    bf16* VT  = Kp + MD;    // total 6*MD + 4*WN ~= 58.7 MB
    bf16* AO  = Qp;         // alias: safe (see attn_kernel note)

    const int M = B_ * S_;  // 4096

    // 1) convert all f32 operands to bf16 (one launch, 7 regions)
    cvt_kernel<<<dim3((int)(MD / 4 / 256), 7), 256, 0, stream>>>(
        q, k, v, Wq, Wk, Wv, Wo, qb, kb, vb, wqb, wkb, wvb, wob,
        (int)MD, (int)WN);

    // 2) QKV projections, XCD-swizzled 1-D grid (768 = 8x * 32y * 3z), BK=64
    gemm_bt_kernel<bf16, true, 128><<<dim3(768), 256, 0, stream>>>(
        qb, kb, vb, wqb, wkb, wvb, bq, bk, bv, Qp, Kp, VT, M, D_, D_);

    // 3) causal flash attention: R9 structure + T5 setprio on MFMA clusters
    attn_kernel<<<dim3(512), 256, 0, stream>>>(Qp, Kp, VT, AO);

    // 4) output projection -> f32 out, XCD-swizzled 1-D grid (512), BK=64
    gemm_bt_kernel<float, false, 64><<<dim3(512), 256, 0, stream>>>(
        AO, AO, AO, wob, wob, wob, bo, bo, bo, out, out, out, M, D_, D_);
}